// Round 2
// baseline (322.748 us; speedup 1.0000x reference)
//
#include <hip/hip_runtime.h>
#include <hip/hip_bf16.h>

// Gram matrix: G = X @ X^T, X = [512, 65536] fp32, out = [512, 512] fp32.
// Round 2: register-prefetch pipeline (overlap global-load latency with MFMA),
// splitK=64 (4 blocks/CU), LDS stride 34 (odd dword stride kills the 8-way
// bank conflict that LDSS=40 had: gcd(20dw,32)=4 -> 8 banks for 64 lanes).

typedef short bf16x8 __attribute__((ext_vector_type(8)));   // 8 bf16 = 4 VGPRs
typedef float f32x4  __attribute__((ext_vector_type(4)));   // MFMA acc

#define HW      65536
#define CDIM    512
#define SPLITK  64
#define KC      (HW / SPLITK)    // 1024 K per block
#define BK      32               // K per LDS stage = MFMA K
#define ITERS   (KC / BK)        // 32
#define LDSS    34               // LDS row stride in bf16 = 17 dwords (odd)

__device__ __forceinline__ short f2bf(float f) {
    __hip_bfloat16 h = __float2bfloat16(f);   // RNE
    short s;
    __builtin_memcpy(&s, &h, sizeof(short));
    return s;
}

__global__ __launch_bounds__(256, 2)
void gram_kernel(const float* __restrict__ X, float* __restrict__ out) {
    const int tile  = blockIdx.x;       // 0..15  -> (ti, tj) output 128x128 tile
    const int ti    = tile >> 2;
    const int tj    = tile & 3;
    const int chunk = blockIdx.y;       // 0..SPLITK-1

    __shared__ short As[128 * LDSS];    // 8704 B each
    __shared__ short Bs[128 * LDSS];

    const int t    = threadIdx.x;
    const int wave = t >> 6;
    const int lane = t & 63;
    const int wm   = wave & 1;          // 2x2 wave grid, each wave = 64x64
    const int wn   = wave >> 1;

    // --- staging mapping: 2 threads per row, 16 consecutive fp32 each ---
    const int srow  = t >> 1;           // 0..127
    const int shalf = (t & 1) * 16;     // k offset 0 or 16
    const float* pa = X + (size_t)(ti * 128 + srow) * HW + chunk * KC + shalf;
    const float* pb = X + (size_t)(tj * 128 + srow) * HW + chunk * KC + shalf;
    short* wa = As + srow * LDSS + shalf;
    short* wb = Bs + srow * LDSS + shalf;

    // --- fragment read offsets (A-operand: m = lane&15, k-group = lane>>4) ---
    const int fm = lane & 15;
    const int kg = lane >> 4;           // 0..3, each group = 8 contiguous k
    int a_off[4], b_off[4];
#pragma unroll
    for (int i = 0; i < 4; ++i) {
        a_off[i] = (wm * 64 + i * 16 + fm) * LDSS + kg * 8;
        b_off[i] = (wn * 64 + i * 16 + fm) * LDSS + kg * 8;
    }

    f32x4 acc[4][4];
#pragma unroll
    for (int i = 0; i < 4; ++i)
#pragma unroll
        for (int j = 0; j < 4; ++j)
            acc[i][j] = (f32x4){0.f, 0.f, 0.f, 0.f};

    // --- prologue: load iteration 0's data into registers ---
    float4 ga0 = *(const float4*)(pa + 0);
    float4 ga1 = *(const float4*)(pa + 4);
    float4 ga2 = *(const float4*)(pa + 8);
    float4 ga3 = *(const float4*)(pa + 12);
    float4 gb0 = *(const float4*)(pb + 0);
    float4 gb1 = *(const float4*)(pb + 4);
    float4 gb2 = *(const float4*)(pb + 8);
    float4 gb3 = *(const float4*)(pb + 12);

    for (int it = 0; it < ITERS; ++it) {
        // convert current registers to bf16
        bf16x8 va0, va1, vb0, vb1;
        va0[0] = f2bf(ga0.x); va0[1] = f2bf(ga0.y); va0[2] = f2bf(ga0.z); va0[3] = f2bf(ga0.w);
        va0[4] = f2bf(ga1.x); va0[5] = f2bf(ga1.y); va0[6] = f2bf(ga1.z); va0[7] = f2bf(ga1.w);
        va1[0] = f2bf(ga2.x); va1[1] = f2bf(ga2.y); va1[2] = f2bf(ga2.z); va1[3] = f2bf(ga2.w);
        va1[4] = f2bf(ga3.x); va1[5] = f2bf(ga3.y); va1[6] = f2bf(ga3.z); va1[7] = f2bf(ga3.w);
        vb0[0] = f2bf(gb0.x); vb0[1] = f2bf(gb0.y); vb0[2] = f2bf(gb0.z); vb0[3] = f2bf(gb0.w);
        vb0[4] = f2bf(gb1.x); vb0[5] = f2bf(gb1.y); vb0[6] = f2bf(gb1.z); vb0[7] = f2bf(gb1.w);
        vb1[0] = f2bf(gb2.x); vb1[1] = f2bf(gb2.y); vb1[2] = f2bf(gb2.z); vb1[3] = f2bf(gb2.w);
        vb1[4] = f2bf(gb3.x); vb1[5] = f2bf(gb3.y); vb1[6] = f2bf(gb3.z); vb1[7] = f2bf(gb3.w);

        __syncthreads();   // previous iteration's LDS reads complete
        *(bf16x8*)(wa + 0) = va0;
        *(bf16x8*)(wa + 8) = va1;
        *(bf16x8*)(wb + 0) = vb0;
        *(bf16x8*)(wb + 8) = vb1;
        __syncthreads();   // stage visible to all waves

        // --- prefetch next iteration's global data; latency overlaps the
        //     MFMAs + ds_reads below (vmcnt wait lands at next loop top) ---
        const int adv = (it + 1 < ITERS) ? BK : 0;   // last iter: re-read (discarded)
        pa += adv;
        pb += adv;
        ga0 = *(const float4*)(pa + 0);
        ga1 = *(const float4*)(pa + 4);
        ga2 = *(const float4*)(pa + 8);
        ga3 = *(const float4*)(pa + 12);
        gb0 = *(const float4*)(pb + 0);
        gb1 = *(const float4*)(pb + 4);
        gb2 = *(const float4*)(pb + 8);
        gb3 = *(const float4*)(pb + 12);

        bf16x8 af[4], bfr[4];
#pragma unroll
        for (int i = 0; i < 4; ++i) af[i]  = *(const bf16x8*)(As + a_off[i]);
#pragma unroll
        for (int j = 0; j < 4; ++j) bfr[j] = *(const bf16x8*)(Bs + b_off[j]);

#pragma unroll
        for (int i = 0; i < 4; ++i)
#pragma unroll
            for (int j = 0; j < 4; ++j)
                acc[i][j] = __builtin_amdgcn_mfma_f32_16x16x32_bf16(
                    af[i], bfr[j], acc[i][j], 0, 0, 0);
    }

    // --- epilogue: atomic accumulate partials ---
    // C/D layout (verified m89/m91): col = lane&15, row = (lane>>4)*4 + reg
    const int orow0 = ti * 128 + wm * 64 + (lane >> 4) * 4;
    const int ocol0 = tj * 128 + wn * 64 + (lane & 15);
#pragma unroll
    for (int i = 0; i < 4; ++i)
#pragma unroll
        for (int j = 0; j < 4; ++j)
#pragma unroll
            for (int r = 0; r < 4; ++r) {
                const int row = orow0 + i * 16 + r;
                const int col = ocol0 + j * 16;
                atomicAdd(out + row * CDIM + col, acc[i][j][r]);
            }
}

extern "C" void kernel_launch(void* const* d_in, const int* in_sizes, int n_in,
                              void* d_out, int out_size, void* d_ws, size_t ws_size,
                              hipStream_t stream) {
    const float* x = (const float*)d_in[0];
    float* out = (float*)d_out;

    // zero the accumulator (harness poisons d_out with 0xAA before every launch)
    hipMemsetAsync(d_out, 0, (size_t)out_size * sizeof(float), stream);

    dim3 grid(16, SPLITK);   // 16 output tiles x 64 K-chunks = 1024 blocks
    dim3 block(256);
    gram_kernel<<<grid, block, 0, stream>>>(x, out);
}

// Round 3
// 297.044 us; speedup vs baseline: 1.0865x; 1.0865x over previous
//
#include <hip/hip_runtime.h>
#include <hip/hip_bf16.h>

// Gram matrix: G = X @ X^T, X = [512, 65536] fp32, out = [512, 512] fp32.
// Round 3: BM=256 tiles, 1024-thread blocks (16 waves, 4x4 wave grid),
// grid = 4 tiles x splitK 64 = 256 blocks = exactly 1 resident block/CU.
// Rationale: per-iter compute window (~1000 cyc: 16 waves x (8 ds_read_b128
// + 16 MFMA)) now exceeds global-load latency (~900 cyc), so the depth-1
// register prefetch actually hides it — rounds 1/2 had a ~250 cyc window and
// were latency-serialized (LLC-warm replays at FETCH~0 still took 190 us).
// Traffic: 1.07 GB -> 402 MB (diag tiles stage their panel once, A=B).
// Note: SQ_LDS_BANK_CONFLICT ~= 8/ds_read_b128 is the inherent 256dw/32bank
// cost, not a real conflict (identical count across LDSS=40 and 34).

typedef short bf16x8 __attribute__((ext_vector_type(8)));   // 8 bf16 = 4 VGPRs
typedef float f32x4  __attribute__((ext_vector_type(4)));   // MFMA acc

#define HW      65536
#define CDIM    512
#define BM      256
#define BK      32               // K per LDS stage = MFMA K
#define SPLITK  64
#define KC      (HW / SPLITK)    // 1024 K per block
#define ITERS   (KC / BK)        // 32
#define LDSS    34               // LDS row stride in bf16 = 17 dwords (odd)

__device__ __forceinline__ short f2bf(float f) {
    __hip_bfloat16 h = __float2bfloat16(f);   // RNE
    short s;
    __builtin_memcpy(&s, &h, sizeof(short));
    return s;
}

__device__ __forceinline__ bf16x8 cvt8(float4 a, float4 b) {
    bf16x8 v;
    v[0] = f2bf(a.x); v[1] = f2bf(a.y); v[2] = f2bf(a.z); v[3] = f2bf(a.w);
    v[4] = f2bf(b.x); v[5] = f2bf(b.y); v[6] = f2bf(b.z); v[7] = f2bf(b.w);
    return v;
}

__global__ __launch_bounds__(1024, 4)
void gram_kernel(const float* __restrict__ X, float* __restrict__ out) {
    const int tile  = blockIdx.x;       // 0..3 -> 2x2 grid of 256x256 tiles
    const int ti    = tile >> 1;
    const int tj    = tile & 1;
    const bool diag = (ti == tj);       // block-uniform
    const int chunk = blockIdx.y;       // 0..SPLITK-1

    __shared__ short As[BM * LDSS];     // 17408 B
    __shared__ short Bs[BM * LDSS];     // 17408 B (unused content on diag tiles)

    const int t    = threadIdx.x;
    const int wave = t >> 6;
    const int lane = t & 63;
    const int wm   = wave & 3;          // 4x4 wave grid, each wave = 64x64 out
    const int wn   = wave >> 2;

    // --- staging mapping (block-uniform branch) ---
    // non-diag: 512 threads stage A (16 fp32 each), 512 stage B.
    //   row = (t&511)>>1, k-offset = (t&1)*16
    // diag: all 1024 threads stage the single shared panel (8 fp32 each).
    //   row = t>>2, k-offset = (t&3)*8
    const float* ps;
    short* ws;
    if (diag) {
        const int r  = t >> 2;
        const int ko = (t & 3) * 8;
        ps = X + (size_t)(ti * BM + r) * HW + chunk * KC + ko;
        ws = As + r * LDSS + ko;
    } else {
        const bool pb = (t >= 512);
        const int r   = (t & 511) >> 1;
        const int ko  = (t & 1) * 16;
        ps = X + (size_t)((pb ? tj : ti) * BM + r) * HW + chunk * KC + ko;
        ws = (pb ? Bs : As) + r * LDSS + ko;
    }

    // --- fragment read offsets (m = lane&15, k-group = lane>>4) ---
    const int fm = lane & 15;
    const int kg = lane >> 4;
    const short* b_base = diag ? As : Bs;   // diag tiles: B frags read the A panel
    int a_off[4], b_off[4];
#pragma unroll
    for (int i = 0; i < 4; ++i) {
        a_off[i] = (wm * 64 + i * 16 + fm) * LDSS + kg * 8;
        b_off[i] = (wn * 64 + i * 16 + fm) * LDSS + kg * 8;
    }

    f32x4 acc[4][4];
#pragma unroll
    for (int i = 0; i < 4; ++i)
#pragma unroll
        for (int j = 0; j < 4; ++j)
            acc[i][j] = (f32x4){0.f, 0.f, 0.f, 0.f};

    // --- prologue: prefetch iteration 0 into registers ---
    float4 p0, p1, p2, p3;
    p0 = *(const float4*)(ps + 0);
    p1 = *(const float4*)(ps + 4);
    if (!diag) {
        p2 = *(const float4*)(ps + 8);
        p3 = *(const float4*)(ps + 12);
    }

    for (int it = 0; it < ITERS; ++it) {
        // convert current prefetch to bf16
        bf16x8 v0 = cvt8(p0, p1);
        bf16x8 v1;
        if (!diag) v1 = cvt8(p2, p3);

        __syncthreads();   // previous iteration's LDS reads complete
        *(bf16x8*)(ws + 0) = v0;
        if (!diag) *(bf16x8*)(ws + 8) = v1;
        __syncthreads();   // stage visible to all waves

        // --- prefetch next iteration; latency overlaps ds_reads + MFMAs ---
        const int adv = (it + 1 < ITERS) ? BK : 0;  // last iter: harmless re-read
        ps += adv;
        p0 = *(const float4*)(ps + 0);
        p1 = *(const float4*)(ps + 4);
        if (!diag) {
            p2 = *(const float4*)(ps + 8);
            p3 = *(const float4*)(ps + 12);
        }

        bf16x8 af[4], bfr[4];
#pragma unroll
        for (int i = 0; i < 4; ++i) af[i]  = *(const bf16x8*)(As + a_off[i]);
#pragma unroll
        for (int j = 0; j < 4; ++j) bfr[j] = *(const bf16x8*)(b_base + b_off[j]);

#pragma unroll
        for (int i = 0; i < 4; ++i)
#pragma unroll
            for (int j = 0; j < 4; ++j)
                acc[i][j] = __builtin_amdgcn_mfma_f32_16x16x32_bf16(
                    af[i], bfr[j], acc[i][j], 0, 0, 0);
    }

    // --- epilogue: atomic accumulate partials ---
    // C/D layout (verified m89/m91): col = lane&15, row = (lane>>4)*4 + reg
    const int orow0 = ti * BM + wm * 64 + (lane >> 4) * 4;
    const int ocol0 = tj * BM + wn * 64 + fm;
#pragma unroll
    for (int i = 0; i < 4; ++i)
#pragma unroll
        for (int j = 0; j < 4; ++j)
#pragma unroll
            for (int r = 0; r < 4; ++r) {
                const int row = orow0 + i * 16 + r;
                const int col = ocol0 + j * 16;
                atomicAdd(out + row * CDIM + col, acc[i][j][r]);
            }
}

extern "C" void kernel_launch(void* const* d_in, const int* in_sizes, int n_in,
                              void* d_out, int out_size, void* d_ws, size_t ws_size,
                              hipStream_t stream) {
    const float* x = (const float*)d_in[0];
    float* out = (float*)d_out;

    // zero the accumulator (harness poisons d_out with 0xAA before every launch)
    hipMemsetAsync(d_out, 0, (size_t)out_size * sizeof(float), stream);

    dim3 grid(4, SPLITK);   // 4 output tiles x 64 K-chunks = 256 blocks (1/CU)
    dim3 block(1024);
    gram_kernel<<<grid, block, 0, stream>>>(x, out);
}